// Round 5
// baseline (27241.904 us; speedup 1.0000x reference)
//
#include <hip/hip_runtime.h>
#include <math.h>

// ESN forward: x_{t+1} = 0.1*x_t + 0.9*tanh(W_in @ u_t + W @ x_t); y_t = Wout @ x_{t+1}
// W sparse (5%) -> padded ELL in ws. 128 cooperative WGs x 256 thr, fence-free.
// R5: tagged-data exchange (epoch<<32|fbits, relaxed agent atomics) with
// LOW-CONTENTION detection: 128 sentinel pollers per WG (one word per
// publishing WG), then ONE bulk tagged load + verify/retry. Gather work
// halved per WG (32 rows/WG) -> half the LDS-pipe serialization.

#define NX 4096
#define NU 128
#define NY 64
#define TSTEPS 4096
#define CAP 352            // padded nnz per row (mean 204.8, sd 13.9)
#define WGS 128
#define TPB 256
#define RPW (NX / WGS)     // 32 rows per workgroup
#define TPR (TPB / RPW)    // 8 threads per row
#define EPT (CAP / TPR)    // 44 ELL entries per thread (contiguous chunk)
#define UPT (NU / TPR)     // 16 W_in entries per thread (contiguous chunk)
#define XW  (NX / TPB)     // 16 packed words bulk-loaded per thread

typedef unsigned long long u64;

// --- Kernel 1: deterministic dense->ELL compaction, one block per row ---
__global__ void build_ell_kernel(const float* __restrict__ W, int2* __restrict__ ell) {
    const int r = blockIdx.x;
    const int tid = threadIdx.x;
    const int wv = tid >> 6, ln = tid & 63;
    __shared__ int wave_tot[4];
    __shared__ int base;
    if (tid == 0) base = 0;
    __syncthreads();
    const float* row = W + (size_t)r * NX;
    int2* out = ell + (size_t)r * CAP;
    for (int chunk = 0; chunk < NX; chunk += 256) {
        float w = row[chunk + tid];
        bool p = (w != 0.0f);
        unsigned long long m = __ballot(p);
        int lp = (int)__popcll(m & ((1ull << ln) - 1ull));
        if (ln == 63) wave_tot[wv] = lp + (p ? 1 : 0);
        __syncthreads();
        int wbase = 0;
        #pragma unroll
        for (int i = 0; i < 4; ++i)
            if (i < wv) wbase += wave_tot[i];
        int tot = wave_tot[0] + wave_tot[1] + wave_tot[2] + wave_tot[3];
        if (p) {
            int o = base + wbase + lp;
            if (o < CAP) out[o] = make_int2(chunk + tid, __float_as_int(w));
        }
        __syncthreads();
        if (tid == 0) base += tot;
        __syncthreads();
    }
    // zero-pad remainder: col=0, val=0 contributes exactly 0
    for (int o = base + tid; o < CAP; o += 256) out[o] = make_int2(0, 0);
}

// --- Kernel 2: cooperative sequential recurrence ---
__global__ void __launch_bounds__(TPB, 1) esn_kernel(
    const float* __restrict__ UT, const float* __restrict__ x0,
    const float* __restrict__ Win, const float* __restrict__ Wout,
    const int2* __restrict__ ell, u64* __restrict__ xbuf,  // [2][NX] packed
    float* __restrict__ Y)
{
    __shared__ __align__(16) float xl[2][NX];
    __shared__ float red[TPB / 64];

    const int tid = threadIdx.x;
    const int wg  = blockIdx.x;              // 0..127
    const int grp = tid >> 3;                // row group within WG (0..31)
    const int ln  = tid & 7;                 // lane within row group
    const int r   = wg * RPW + grp;          // global row this 8-thread group owns

    // contiguous per-thread slices (static data: stays L1/L2-cached, never fenced)
    const float4* winrow = (const float4*)(Win + (size_t)r * NU + ln * UPT);
    const int4*   ellrow = (const int4*)  (ell + (size_t)r * CAP + ln * EPT);
    const float*  woutrow = (wg < NY) ? (Wout + (size_t)wg * NX) : (const float*)0;

    for (int t = 0; t < TSTEPS; ++t) {
        float* xc = xl[t & 1];

        // ---- x-independent partial: acc = Win[r,:] @ u_t ----
        float acc = 0.0f;
        {
            const float4* u4 = (const float4*)(UT + (size_t)t * NU + ln * UPT);
            #pragma unroll
            for (int i = 0; i < UPT / 4; ++i) {
                float4 w = winrow[i], u = u4[i];
                acc += w.x * u.x + w.y * u.y + w.z * u.z + w.w * u.w;
            }
        }

        // ---- stage x_t into LDS ----
        if (t == 0) {
            const float4* xs4 = (const float4*)x0;
            float4* xl4 = (float4*)xc;
            #pragma unroll
            for (int i = tid; i < NX / 4; i += TPB) xl4[i] = xs4[i];
        } else {
            const u64* xs = xbuf + (size_t)(t & 1) * NX;
            // detection: threads 0..127 each spin on ONE sentinel word
            // (first row of each publishing WG). Bounded poll traffic.
            if (tid < WGS) {
                const u64* sp = xs + (size_t)tid * RPW;
                while ((unsigned)(__hip_atomic_load(sp, __ATOMIC_RELAXED,
                                                    __HIP_MEMORY_SCOPE_AGENT) >> 32)
                       != (unsigned)t) { }
            }
            __syncthreads();
            // one bulk tagged load; verify per-word, retry rare stragglers
            u64 v[XW];
            #pragma unroll
            for (int j = 0; j < XW; ++j)
                v[j] = __hip_atomic_load(xs + tid + TPB * j,
                                         __ATOMIC_RELAXED, __HIP_MEMORY_SCOPE_AGENT);
            bool any = true;
            while (any) {
                any = false;
                #pragma unroll
                for (int j = 0; j < XW; ++j)
                    if ((unsigned)(v[j] >> 32) != (unsigned)t) {
                        v[j] = __hip_atomic_load(xs + tid + TPB * j,
                                                 __ATOMIC_RELAXED, __HIP_MEMORY_SCOPE_AGENT);
                        any = true;
                    }
            }
            #pragma unroll
            for (int j = 0; j < XW; ++j)
                xc[tid + TPB * j] = __uint_as_float((unsigned)v[j]);
        }
        __syncthreads();

        // ---- acc += W[r,:] @ x_t (sparse ELL gather from LDS) ----
        #pragma unroll 4
        for (int i = 0; i < EPT / 2; ++i) {
            int4 cv = ellrow[i];   // two (col,val) pairs
            acc += __int_as_float(cv.y) * xc[cv.x]
                 + __int_as_float(cv.w) * xc[cv.z];
        }
        acc += __shfl_down(acc, 4, 8);
        acc += __shfl_down(acc, 2, 8);
        acc += __shfl_down(acc, 1, 8);
        if (ln == 0) {
            float xn = 0.1f * xc[r] + 0.9f * tanhf(acc);
            u64 packed = ((u64)(unsigned)(t + 1) << 32) | (u64)__float_as_uint(xn);
            __hip_atomic_store(xbuf + (size_t)((t + 1) & 1) * NX + r, packed,
                               __ATOMIC_RELAXED, __HIP_MEMORY_SCOPE_AGENT);
        }

        // ---- readout Y[t-1] = Wout[wg] . x_t (off critical path; WGs 0..63) ----
        if (wg < NY && t > 0) {
            float a = 0.0f;
            for (int i = tid; i < NX; i += TPB) a += woutrow[i] * xc[i];
            for (int off = 32; off; off >>= 1) a += __shfl_down(a, off, 64);
            if ((tid & 63) == 0) red[tid >> 6] = a;
            __syncthreads();
            if (tid == 0) {
                float s = 0.0f;
                #pragma unroll
                for (int i = 0; i < TPB / 64; ++i) s += red[i];
                Y[(size_t)(t - 1) * NY + wg] = s;
            }
        }
    }

    // ---- final: stage x_T (epoch TSTEPS, slot 0) and emit Y[T-1] ----
    if (wg < NY) {
        float* xc = xl[0];
        const u64* xs = xbuf + (size_t)(TSTEPS & 1) * NX;
        if (tid < WGS) {
            const u64* sp = xs + (size_t)tid * RPW;
            while ((unsigned)(__hip_atomic_load(sp, __ATOMIC_RELAXED,
                                                __HIP_MEMORY_SCOPE_AGENT) >> 32)
                   != (unsigned)TSTEPS) { }
        }
        __syncthreads();
        u64 v[XW];
        #pragma unroll
        for (int j = 0; j < XW; ++j)
            v[j] = __hip_atomic_load(xs + tid + TPB * j,
                                     __ATOMIC_RELAXED, __HIP_MEMORY_SCOPE_AGENT);
        bool any = true;
        while (any) {
            any = false;
            #pragma unroll
            for (int j = 0; j < XW; ++j)
                if ((unsigned)(v[j] >> 32) != (unsigned)TSTEPS) {
                    v[j] = __hip_atomic_load(xs + tid + TPB * j,
                                             __ATOMIC_RELAXED, __HIP_MEMORY_SCOPE_AGENT);
                    any = true;
                }
        }
        #pragma unroll
        for (int j = 0; j < XW; ++j)
            xc[tid + TPB * j] = __uint_as_float((unsigned)v[j]);
        __syncthreads();

        float a = 0.0f;
        for (int i = tid; i < NX; i += TPB) a += woutrow[i] * xc[i];
        for (int off = 32; off; off >>= 1) a += __shfl_down(a, off, 64);
        if ((tid & 63) == 0) red[tid >> 6] = a;
        __syncthreads();
        if (tid == 0) {
            float s = 0.0f;
            #pragma unroll
            for (int i = 0; i < TPB / 64; ++i) s += red[i];
            Y[(size_t)(TSTEPS - 1) * NY + wg] = s;
        }
    }
}

extern "C" void kernel_launch(void* const* d_in, const int* in_sizes, int n_in,
                              void* d_out, int out_size, void* d_ws, size_t ws_size,
                              hipStream_t stream) {
    const float* UT   = (const float*)d_in[0];  // [T, NU]
    const float* x0   = (const float*)d_in[1];  // [NX]
    const float* Win  = (const float*)d_in[2];  // [NX, NU]
    const float* W    = (const float*)d_in[3];  // [NX, NX]
    const float* Wout = (const float*)d_in[4];  // [NY, NX]
    float* Y = (float*)d_out;                   // [T*NY]

    char* ws = (char*)d_ws;
    u64*  xbuf = (u64*)ws;                      // 2*NX packed words = 64 KB
    int2* ell  = (int2*)(ws + 65536);           // NX*CAP*8 = 11,534,336 B

    build_ell_kernel<<<dim3(NX), dim3(256), 0, stream>>>(W, ell);

    void* args[] = { (void*)&UT, (void*)&x0, (void*)&Win, (void*)&Wout,
                     (void*)&ell, (void*)&xbuf, (void*)&Y };
    hipLaunchCooperativeKernel((const void*)esn_kernel, dim3(WGS), dim3(TPB),
                               args, 0, stream);
}